// Round 5
// baseline (485.138 us; speedup 1.0000x reference)
//
#include <hip/hip_runtime.h>

typedef unsigned short u16;
typedef __attribute__((ext_vector_type(4))) float f32x4;
typedef __attribute__((ext_vector_type(8))) __bf16 bf16x8;

// ---------- helpers ----------
__device__ __forceinline__ u16 f2bf(float f) {
    unsigned int x = __float_as_uint(f);
    x += 0x7fffu + ((x >> 16) & 1u);          // RNE
    return (u16)(x >> 16);
}
__device__ __forceinline__ float bf2f(u16 u) {
    return __uint_as_float(((unsigned int)u) << 16);
}
__device__ __forceinline__ void async16(const void* g, void* l) {
    __builtin_amdgcn_global_load_lds(
        (const __attribute__((address_space(1))) void*)g,
        (__attribute__((address_space(3))) void*)l,
        16, 0, 0);
}
__device__ __forceinline__ void barrier_fence() {
    asm volatile("" ::: "memory");
    __builtin_amdgcn_s_barrier();
    asm volatile("" ::: "memory");
}

// ---------- fp32 -> bf16 convert, all four inputs in one launch ----------
__global__ __launch_bounds__(256)
void cvt_all(const float* __restrict__ x,  const float* __restrict__ wq,
             const float* __restrict__ wkv, const float* __restrict__ wo,
             u16* __restrict__ xb, u16* __restrict__ wqb,
             u16* __restrict__ wkvb, u16* __restrict__ wob)
{
    const int nx = 8388608, nq = 4194304, nkv = 2097152;
    const int i = (blockIdx.x * 256 + threadIdx.x) * 4;
    const float* src; u16* dst; int off;
    if (i < nx)                 { src = x;   dst = xb;   off = i; }
    else if (i < nx + nq)       { src = wq;  dst = wqb;  off = i - nx; }
    else if (i < nx + nq + nkv) { src = wkv; dst = wkvb; off = i - nx - nq; }
    else                        { src = wo;  dst = wob;  off = i - nx - nq - nkv; }
    const float4 v = *(const float4*)(src + off);
    ushort4 o;
    o.x = f2bf(v.x); o.y = f2bf(v.y); o.z = f2bf(v.z); o.w = f2bf(v.w);
    *(ushort4*)(dst + off) = o;
}

// ---------- GEMM1: C = A[M,K] * B[N,K]^T, 128x128 tile (round-4, frozen) ----
template <int MODE>
__global__ __launch_bounds__(256, 3)
void gemm128r(const u16* __restrict__ A,
              const u16* __restrict__ B0,
              const u16* __restrict__ B1,
              u16* __restrict__ C,
              float* __restrict__ Cf,
              u16* __restrict__ vbuf,
              int M, int N, int K)
{
    constexpr int ASZ = 128 * 32;        // u16 per buffer (8 KB)
    __shared__ __align__(16) u16 As[3 * ASZ];
    __shared__ __align__(16) u16 Bs[3 * ASZ];

    const int tid  = threadIdx.x;
    const int w    = tid >> 6;
    const int lane = tid & 63;
    const int fl   = lane & 15;
    const int q4   = lane >> 4;
    const int wm   = w >> 1;             // 0..1 : 64-row slice
    const int wn   = w & 1;              // 0..1 : 64-col slice

    const int gx  = gridDim.x;
    const int nwg = gx * gridDim.y;
    int id = blockIdx.y * gx + blockIdx.x;
    id = (id & 7) * (nwg >> 3) + (id >> 3);
    const int m0 = (id / gx) * 128;
    const int n0 = (id % gx) * 128;

    const u16* Bp = B0;
    int nb = n0;
    if (MODE == 1 && n0 >= 2048) { Bp = B1; nb = n0 - 2048; }

    const int srow = w * 16 + (lane >> 2);
    const int sg   = (lane & 3) ^ ((lane >> 3) & 3);
    const u16* agp = A  + (size_t)(m0 + srow) * K + sg * 8;
    const u16* bgp = Bp + (size_t)(nb + srow) * K + sg * 8;
    const int sLds = w * 512;

    const int cSlot = (q4 ^ ((fl >> 1) & 3)) * 8;

    f32x4 acc[4][4];
    #pragma unroll
    for (int i = 0; i < 4; ++i)
        #pragma unroll
        for (int j = 0; j < 4; ++j)
            acc[i][j] = f32x4{0.f, 0.f, 0.f, 0.f};

    const int NT = K >> 5;               // 64 K-steps

    auto stage = [&](int t, int bf) {    // 4 x global_load_lds per thread
        const size_t kof = (size_t)t * 32;
        async16(agp + kof,                   &As[bf * ASZ + sLds]);
        async16(agp + (size_t)64 * K + kof,  &As[bf * ASZ + 2048 + sLds]);
        async16(bgp + kof,                   &Bs[bf * ASZ + sLds]);
        async16(bgp + (size_t)64 * K + kof,  &Bs[bf * ASZ + 2048 + sLds]);
    };

    stage(0, 0);
    stage(1, 1);

    int bf = 0;                          // buffer holding tile t
    for (int t = 0; t < NT; ++t) {
        if (t < NT - 1) asm volatile("s_waitcnt vmcnt(4)" ::: "memory");
        else            asm volatile("s_waitcnt vmcnt(0)" ::: "memory");
        barrier_fence();
        const int bf2 = (bf + 2 >= 3) ? bf - 1 : bf + 2;
        if (t + 2 < NT) stage(t + 2, bf2);

        const int ab = bf * ASZ + (wm * 64 + fl) * 32 + cSlot;
        const int bb = bf * ASZ + (wn * 64 + fl) * 32 + cSlot;
        bf16x8 a[4], b[4];
        #pragma unroll
        for (int mt = 0; mt < 4; ++mt)
            a[mt] = *(const bf16x8*)&As[ab + mt * 512];
        #pragma unroll
        for (int nt = 0; nt < 4; ++nt)
            b[nt] = *(const bf16x8*)&Bs[bb + nt * 512];

        #pragma unroll
        for (int mt = 0; mt < 4; ++mt)
            #pragma unroll
            for (int nt = 0; nt < 4; ++nt)
                acc[mt][nt] = __builtin_amdgcn_mfma_f32_16x16x32_bf16(
                    a[mt], b[nt], acc[mt][nt], 0, 0, 0);

        bf = (bf + 1 >= 3) ? 0 : bf + 1;
    }

    #pragma unroll
    for (int mt = 0; mt < 4; ++mt) {
        #pragma unroll
        for (int nt = 0; nt < 4; ++nt) {
            const int colb = n0 + wn * 64 + nt * 16 + fl;
            #pragma unroll
            for (int r = 0; r < 4; ++r) {
                const int row = m0 + wm * 64 + mt * 16 + q4 * 4 + r;
                if (MODE == 0) {
                    Cf[(size_t)row * N + colb] = acc[mt][nt][r];
                } else {
                    const u16 val = f2bf(acc[mt][nt][r]);
                    if (colb < 2560) {
                        C[(size_t)row * 3072 + colb] = val;
                    } else {
                        const int f  = colb - 2560;
                        const int tt = row & 2047;
                        const int bb2 = row >> 11;
                        vbuf[((size_t)((bb2 << 2) + (f >> 7)) * 128 + (f & 127)) * 2048 + tt] = val;
                    }
                }
            }
        }
    }
}

// ---------- GEMM2: Cf = A[M,K] * B[N,K]^T, 64x128 tile, 4 blocks/CU ---------
// Same 3-rotating-buffer counted-vmcnt structure as gemm128r, smaller tile:
// grid 1024 wgs -> 4 blocks/CU (36 KiB LDS), restoring the cross-block
// overlap MODE0 lacked at 512 wgs / 2 per CU.
__global__ __launch_bounds__(256, 4)
void gemm64(const u16* __restrict__ A,
            const u16* __restrict__ B0,
            float* __restrict__ Cf,
            int M, int N, int K)
{
    constexpr int ASZ = 64 * 32;         // 4 KB / buffer
    constexpr int BSZ = 128 * 32;        // 8 KB / buffer
    __shared__ __align__(16) u16 As[3 * ASZ];
    __shared__ __align__(16) u16 Bs[3 * BSZ];

    const int tid  = threadIdx.x;
    const int w    = tid >> 6;
    const int lane = tid & 63;
    const int fl   = lane & 15;
    const int q4   = lane >> 4;
    const int wm   = w >> 1;             // 0..1 : 32-row slice
    const int wn   = w & 1;              // 0..1 : 64-col slice

    const int gx  = gridDim.x;
    const int nwg = gx * gridDim.y;
    int id = blockIdx.y * gx + blockIdx.x;
    id = (id & 7) * (nwg >> 3) + (id >> 3);
    const int m0 = (id / gx) * 64;
    const int n0 = (id % gx) * 128;

    const int srow = w * 16 + (lane >> 2);          // 0..63
    const int sg   = (lane & 3) ^ ((lane >> 3) & 3);
    const u16* agp = A  + (size_t)(m0 + srow) * K + sg * 8;
    const u16* bgp = B0 + (size_t)(n0 + srow) * K + sg * 8;
    const int sLds = w * 512;

    const int cSlot = (q4 ^ ((fl >> 1) & 3)) * 8;

    f32x4 acc[2][4];
    #pragma unroll
    for (int i = 0; i < 2; ++i)
        #pragma unroll
        for (int j = 0; j < 4; ++j)
            acc[i][j] = f32x4{0.f, 0.f, 0.f, 0.f};

    const int NT = K >> 5;

    auto stage = [&](int t, int bf) {    // 3 x global_load_lds per thread
        const size_t kof = (size_t)t * 32;
        async16(agp + kof,                  &As[bf * ASZ + sLds]);
        async16(bgp + kof,                  &Bs[bf * BSZ + sLds]);
        async16(bgp + (size_t)64 * K + kof, &Bs[bf * BSZ + 2048 + sLds]);
    };

    stage(0, 0);
    stage(1, 1);

    int bf = 0;
    for (int t = 0; t < NT; ++t) {
        if (t < NT - 1) asm volatile("s_waitcnt vmcnt(3)" ::: "memory");
        else            asm volatile("s_waitcnt vmcnt(0)" ::: "memory");
        barrier_fence();
        const int bf2 = (bf + 2 >= 3) ? bf - 1 : bf + 2;
        if (t + 2 < NT) stage(t + 2, bf2);

        const int ab = bf * ASZ + (wm * 32 + fl) * 32 + cSlot;
        const int bb = bf * BSZ + (wn * 64 + fl) * 32 + cSlot;
        bf16x8 a[2], b[4];
        #pragma unroll
        for (int mt = 0; mt < 2; ++mt)
            a[mt] = *(const bf16x8*)&As[ab + mt * 512];
        #pragma unroll
        for (int nt = 0; nt < 4; ++nt)
            b[nt] = *(const bf16x8*)&Bs[bb + nt * 512];

        #pragma unroll
        for (int mt = 0; mt < 2; ++mt)
            #pragma unroll
            for (int nt = 0; nt < 4; ++nt)
                acc[mt][nt] = __builtin_amdgcn_mfma_f32_16x16x32_bf16(
                    a[mt], b[nt], acc[mt][nt], 0, 0, 0);

        bf = (bf + 1 >= 3) ? 0 : bf + 1;
    }

    #pragma unroll
    for (int mt = 0; mt < 2; ++mt)
        #pragma unroll
        for (int nt = 0; nt < 4; ++nt) {
            const int colb = n0 + wn * 64 + nt * 16 + fl;
            #pragma unroll
            for (int r = 0; r < 4; ++r) {
                const int row = m0 + wm * 32 + mt * 16 + q4 * 4 + r;
                Cf[(size_t)row * N + colb] = acc[mt][nt][r];
            }
        }
}

// ---------- RoPE (in place; q heads also get * 1/sqrt(D) folded in) ---------
__global__ __launch_bounds__(256)
void rope_kernel(u16* __restrict__ qkv)
{
    const int idx = blockIdx.x * 256 + threadIdx.x;
    const int i   = idx & 63;
    const int t1  = idx >> 6;
    const int hh  = t1 % 20;
    const int m   = t1 / 20;
    const int pos = m & 2047;
    const bool isq = (hh < 16);
    const int col = isq ? (hh << 7) : (2048 + ((hh - 16) << 7));
    u16* p = qkv + (size_t)m * 3072 + col;

    const float inv = powf(10000.0f, -(float)(2 * i) * (1.0f / 128.0f));
    const float ang = (float)pos * inv;
    float s, c;
    sincosf(ang, &s, &c);
    const float sc = isq ? 0.08838834764831845f : 1.0f;   // 1/sqrt(128)
    const float x1 = bf2f(p[i]);
    const float x2 = bf2f(p[i + 64]);
    p[i]      = f2bf((x1 * c - x2 * s) * sc);
    p[i + 64] = f2bf((x2 * c + x1 * s) * sc);
}

// ---------- causal flash attention (cache-fed, barrier-free) ----------------
// K/V working set (8 panels x 512 KB = 4 MB) is L2/L3-resident, so LDS
// staging + barriers were pure overhead (guide m169). K and V fragments are
// read directly from global (hoisted row pointers; 16 rows x 64 B segments).
// Dual-context PV shares each V load: both P sets written to a widened Ps
// row, one lgkmcnt(0), one V pass. Ps rows are per-wave-private -> NO
// barriers anywhere. Work-paired causal scheme unchanged (lo=bx, hi=31-bx).
__global__ __launch_bounds__(256, 2)
void attn_kernel(const u16* __restrict__ qkv,
                 const u16* __restrict__ vsrc,
                 u16* __restrict__ y)
{
    constexpr int T = 2048;
    const int lo  = blockIdx.x;          // 0..15
    const int hi  = 31 - lo;             // 16..31
    const int bh  = blockIdx.y;
    const int b   = bh >> 4;
    const int h   = bh & 15;
    const int kvh = h >> 2;

    const int tid  = threadIdx.x;
    const int w    = tid >> 6;
    const int lane = tid & 63;
    const int fl   = lane & 15;
    const int q4   = lane >> 4;

    // [q][ kv 0..63 : ctx1 | 64..127 : ctx0 | 8 pad ]  (stride 136 u16:
    // 272 B -> 2-way bank alias on b128 reads = free; 16-B aligned slices)
    __shared__ __align__(16) u16 Ps[64 * 136];

    const u16* Qg = qkv  + (size_t)(b * T) * 3072 + (h << 7);
    const u16* Kg = qkv  + (size_t)(b * T) * 3072 + 2048 + (kvh << 7);
    const u16* Vg = vsrc + (size_t)((b * 4 + kvh) * 128) * T;

    // Q fragments for both tiles (pre-scaled by 1/sqrt(D) in rope)
    bf16x8 qf0[4], qf1[4];
    #pragma unroll
    for (int kc = 0; kc < 4; ++kc) {
        qf0[kc] = *(const bf16x8*)&Qg[(size_t)(lo * 64 + w * 16 + fl) * 3072 + kc * 32 + q4 * 8];
        qf1[kc] = *(const bf16x8*)&Qg[(size_t)(hi * 64 + w * 16 + fl) * 3072 + kc * 32 + q4 * 8];
    }

    // hoisted per-lane row pointers for direct K/V fragment loads
    const u16* kr[4];
    #pragma unroll
    for (int nt = 0; nt < 4; ++nt)
        kr[nt] = Kg + (size_t)(nt * 16 + fl) * 3072 + q4 * 8;
    const u16* vr[8];
    #pragma unroll
    for (int dt = 0; dt < 8; ++dt)
        vr[dt] = Vg + (size_t)(dt * 16 + fl) * T + q4 * 8;

    float l0 = 0.f, l1 = 0.f;
    f32x4 o0[8], o1[8];
    #pragma unroll
    for (int dt = 0; dt < 8; ++dt) {
        o0[dt] = f32x4{0.f, 0.f, 0.f, 0.f};
        o1[dt] = f32x4{0.f, 0.f, 0.f, 0.f};
    }

    const int psrow = (w * 16 + fl) * 136;

    for (int j = 0; j <= hi; ++j) {
        const bool dual = (j <= lo);
        const size_t kjo = (size_t)j * 64 * 3072;
        const int    vjo = j * 64;

        // S^T = K * Q^T ; K fragments straight from L2/L3
        f32x4 s0[4], s1[4];
        #pragma unroll
        for (int nt = 0; nt < 4; ++nt) {
            s0[nt] = f32x4{0.f, 0.f, 0.f, 0.f};
            s1[nt] = f32x4{0.f, 0.f, 0.f, 0.f};
        }
        if (dual) {
            #pragma unroll
            for (int kc = 0; kc < 4; ++kc)
                #pragma unroll
                for (int nt = 0; nt < 4; ++nt) {
                    bf16x8 aK = *(const bf16x8*)(kr[nt] + kjo + kc * 32);
                    s1[nt] = __builtin_amdgcn_mfma_f32_16x16x32_bf16(aK, qf1[kc], s1[nt], 0, 0, 0);
                    s0[nt] = __builtin_amdgcn_mfma_f32_16x16x32_bf16(aK, qf0[kc], s0[nt], 0, 0, 0);
                }
        } else {
            #pragma unroll
            for (int kc = 0; kc < 4; ++kc)
                #pragma unroll
                for (int nt = 0; nt < 4; ++nt) {
                    bf16x8 aK = *(const bf16x8*)(kr[nt] + kjo + kc * 32);
                    s1[nt] = __builtin_amdgcn_mfma_f32_16x16x32_bf16(aK, qf1[kc], s1[nt], 0, 0, 0);
                }
        }

        // causal masks (diagonal tiles only; j==lo is always dual, j==hi never)
        if (j == lo || j == hi) {
            const int qloc = w * 16 + fl;
            #pragma unroll
            for (int nt = 0; nt < 4; ++nt)
                #pragma unroll
                for (int r = 0; r < 4; ++r)
                    if (nt * 16 + q4 * 4 + r > qloc) {
                        if (j == lo) s0[nt][r] = -3e38f;
                        else         s1[nt][r] = -3e38f;
                    }
        }

        // exp + P writes for BOTH contexts, then a single lgkmcnt
        if (dual) {
            #pragma unroll
            for (int nt = 0; nt < 4; ++nt) {
                ushort4 pw;
                float p0 = __expf(s0[nt][0]);
                float p1 = __expf(s0[nt][1]);
                float p2 = __expf(s0[nt][2]);
                float p3 = __expf(s0[nt][3]);
                l0 += (p0 + p1) + (p2 + p3);
                pw.x = f2bf(p0); pw.y = f2bf(p1); pw.z = f2bf(p2); pw.w = f2bf(p3);
                *(ushort4*)&Ps[psrow + 64 + nt * 16 + q4 * 4] = pw;
            }
        }
        #pragma unroll
        for (int nt = 0; nt < 4; ++nt) {
            ushort4 pw;
            float p0 = __expf(s1[nt][0]);
            float p1 = __expf(s1[nt][1]);
            float p2 = __expf(s1[nt][2]);
            float p3 = __expf(s1[nt][3]);
            l1 += (p0 + p1) + (p2 + p3);
            pw.x = f2bf(p0); pw.y = f2bf(p1); pw.z = f2bf(p2); pw.w = f2bf(p3);
            *(ushort4*)&Ps[psrow + nt * 16 + q4 * 4] = pw;
        }
        asm volatile("s_waitcnt lgkmcnt(0)" ::: "memory");

        // PV: V fragments straight from cache, shared by both contexts.
        // In-wave DS ordering makes next iteration's Ps writes safe.
        if (dual) {
            #pragma unroll
            for (int kc = 0; kc < 2; ++kc) {
                bf16x8 ap1 = *(const bf16x8*)&Ps[psrow + kc * 32 + q4 * 8];
                bf16x8 ap0 = *(const bf16x8*)&Ps[psrow + 64 + kc * 32 + q4 * 8];
                #pragma unroll
                for (int dt = 0; dt < 8; ++dt) {
                    bf16x8 bv = *(const bf16x8*)(vr[dt] + vjo + kc * 32);
                    o1[dt] = __builtin_amdgcn_mfma_f32_16x16x32_bf16(ap1, bv, o1[dt], 0, 0, 0);
                    o0[dt] = __builtin_amdgcn_mfma_f32_16x16x32_bf16(ap0, bv, o0[dt], 0, 0, 0);
                }
            }
        } else {
            #pragma unroll
            for (int kc = 0; kc < 2; ++kc) {
                bf16x8 ap1 = *(const bf16x8*)&Ps[psrow + kc * 32 + q4 * 8];
                #pragma unroll
                for (int dt = 0; dt < 8; ++dt) {
                    bf16x8 bv = *(const bf16x8*)(vr[dt] + vjo + kc * 32);
                    o1[dt] = __builtin_amdgcn_mfma_f32_16x16x32_bf16(ap1, bv, o1[dt], 0, 0, 0);
                }
            }
        }
    }

    // deferred l reductions + epilogue for both contexts
    l0 += __shfl_xor(l0, 16, 64);
    l0 += __shfl_xor(l0, 32, 64);
    l1 += __shfl_xor(l1, 16, 64);
    l1 += __shfl_xor(l1, 32, 64);
    const float li0 = 1.0f / l0;
    const float li1 = 1.0f / l1;

    float lr0[4], lr1[4];
    #pragma unroll
    for (int r = 0; r < 4; ++r) {
        lr0[r] = __shfl(li0, q4 * 4 + r, 16);
        lr1[r] = __shfl(li1, q4 * 4 + r, 16);
    }
    #pragma unroll
    for (int dt = 0; dt < 8; ++dt)
        #pragma unroll
        for (int r = 0; r < 4; ++r) {
            const int row0 = lo * 64 + w * 16 + q4 * 4 + r;
            const int row1 = hi * 64 + w * 16 + q4 * 4 + r;
            y[(size_t)(b * T + row0) * 2048 + (h << 7) + dt * 16 + fl] =
                f2bf(o0[dt][r] * lr0[r]);
            y[(size_t)(b * T + row1) * 2048 + (h << 7) + dt * 16 + fl] =
                f2bf(o1[dt][r] * lr1[r]);
        }
}

// ---------- launch ----------------------------------------------------------
extern "C" void kernel_launch(void* const* d_in, const int* in_sizes, int n_in,
                              void* d_out, int out_size, void* d_ws, size_t ws_size,
                              hipStream_t stream)
{
    const float* x   = (const float*)d_in[0];
    const float* Wq  = (const float*)d_in[1];
    const float* Wkv = (const float*)d_in[2];
    const float* Wo  = (const float*)d_in[3];
    float* out = (float*)d_out;

    const int nx = 4096 * 2048, nq = 2048 * 2048, nkv = 1024 * 2048, no = 2048 * 2048;

    u16* xb   = (u16*)d_ws;
    u16* wqb  = xb  + nx;
    u16* wkvb = wqb + nq;
    u16* wob  = wkvb + nkv;
    u16* qkv  = wob + no;                            // [4096, 3072]
    u16* vbuf = qkv + (size_t)4096 * 3072;           // V^T [B*KV*128, 2048]
    u16* y    = vbuf + (size_t)2 * 4 * 128 * 2048;   // [4096, 2048]

    const int ntot = nx + nq + nkv + no;
    cvt_all<<<ntot / 1024, 256, 0, stream>>>(x, Wq, Wkv, Wo, xb, wqb, wkvb, wob);

    dim3 g1(3072 / 128, 4096 / 128);                 // 24 x 32 = 768 wgs (%8==0)
    gemm128r<1><<<g1, 256, 0, stream>>>(xb, wqb, wkvb, qkv, nullptr, vbuf, 4096, 3072, 2048);

    rope_kernel<<<(4096 * 20 * 64) / 256, 256, 0, stream>>>(qkv);

    attn_kernel<<<dim3(16, 32), 256, 0, stream>>>(qkv, vbuf, y);

    dim3 g2(2048 / 128, 4096 / 64);                  // 16 x 64 = 1024 wgs (%8==0)
    gemm64<<<g2, 256, 0, stream>>>(y, wob, out, 4096, 2048, 2048);
}

// Round 6
// 273.314 us; speedup vs baseline: 1.7750x; 1.7750x over previous
//
#include <hip/hip_runtime.h>

typedef unsigned short u16;
typedef __attribute__((ext_vector_type(4))) float f32x4;
typedef __attribute__((ext_vector_type(8))) __bf16 bf16x8;

// ---------- helpers ----------
__device__ __forceinline__ u16 f2bf(float f) {
    unsigned int x = __float_as_uint(f);
    x += 0x7fffu + ((x >> 16) & 1u);          // RNE
    return (u16)(x >> 16);
}
__device__ __forceinline__ float bf2f(u16 u) {
    return __uint_as_float(((unsigned int)u) << 16);
}
__device__ __forceinline__ void async16(const void* g, void* l) {
    __builtin_amdgcn_global_load_lds(
        (const __attribute__((address_space(1))) void*)g,
        (__attribute__((address_space(3))) void*)l,
        16, 0, 0);
}
__device__ __forceinline__ void barrier_fence() {
    asm volatile("" ::: "memory");
    __builtin_amdgcn_s_barrier();
    asm volatile("" ::: "memory");
}

// ---------- fp32 -> bf16 convert, all four inputs in one launch ----------
__global__ __launch_bounds__(256)
void cvt_all(const float* __restrict__ x,  const float* __restrict__ wq,
             const float* __restrict__ wkv, const float* __restrict__ wo,
             u16* __restrict__ xb, u16* __restrict__ wqb,
             u16* __restrict__ wkvb, u16* __restrict__ wob)
{
    const int nx = 8388608, nq = 4194304, nkv = 2097152;
    const int i = (blockIdx.x * 256 + threadIdx.x) * 4;
    const float* src; u16* dst; int off;
    if (i < nx)                 { src = x;   dst = xb;   off = i; }
    else if (i < nx + nq)       { src = wq;  dst = wqb;  off = i - nx; }
    else if (i < nx + nq + nkv) { src = wkv; dst = wkvb; off = i - nx - nq; }
    else                        { src = wo;  dst = wob;  off = i - nx - nq - nkv; }
    const float4 v = *(const float4*)(src + off);
    ushort4 o;
    o.x = f2bf(v.x); o.y = f2bf(v.y); o.z = f2bf(v.z); o.w = f2bf(v.w);
    *(ushort4*)(dst + off) = o;
}

// ---------- GEMM1 + fused RoPE: qkv = x * [Wq|Wkv]^T -----------------------
// Round-4 gemm128r structure verbatim (128x128 tile, BK=32, 3 rotating
// buffers, counted vmcnt(4), conflict-free granule swizzle, 3 blocks/CU).
// ONLY change: wave->B-column remap so each wave holds both halves of every
// RoPE pair (d, d+64) in registers: wave wn owns cols {wn*32+0..31} and
// {64+wn*32+0..31}; acc[mt][j] pairs with acc[mt][j+2]. RoPE (+ q 1/sqrt(D))
// applied in the epilogue; separate rope kernel and its qkv re-read deleted.
__global__ __launch_bounds__(256, 3)
void gemm_qkv(const u16* __restrict__ A,
              const u16* __restrict__ B0,
              const u16* __restrict__ B1,
              u16* __restrict__ C,
              u16* __restrict__ vbuf,
              int M, int K)
{
    constexpr int ASZ = 128 * 32;        // u16 per buffer (8 KB)
    __shared__ __align__(16) u16 As[3 * ASZ];
    __shared__ __align__(16) u16 Bs[3 * ASZ];

    const int tid  = threadIdx.x;
    const int w    = tid >> 6;
    const int lane = tid & 63;
    const int fl   = lane & 15;
    const int q4   = lane >> 4;
    const int wm   = w >> 1;             // 0..1 : 64-row slice
    const int wn   = w & 1;              // 0..1 : column group

    const int gx  = gridDim.x;           // 24
    const int nwg = gx * gridDim.y;
    int id = blockIdx.y * gx + blockIdx.x;
    id = (id & 7) * (nwg >> 3) + (id >> 3);
    const int m0 = (id / gx) * 128;
    const int n0 = (id % gx) * 128;

    const u16* Bp = B0;
    int nb = n0;
    if (n0 >= 2048) { Bp = B1; nb = n0 - 2048; }

    const int srow = w * 16 + (lane >> 2);
    const int sg   = (lane & 3) ^ ((lane >> 3) & 3);
    const u16* agp = A  + (size_t)(m0 + srow) * K + sg * 8;
    const u16* bgp = Bp + (size_t)(nb + srow) * K + sg * 8;
    const int sLds = w * 512;

    const int cSlot = (q4 ^ ((fl >> 1) & 3)) * 8;

    f32x4 acc[4][4];
    #pragma unroll
    for (int i = 0; i < 4; ++i)
        #pragma unroll
        for (int j = 0; j < 4; ++j)
            acc[i][j] = f32x4{0.f, 0.f, 0.f, 0.f};

    const int NT = K >> 5;               // 64 K-steps

    auto stage = [&](int t, int bf) {
        const size_t kof = (size_t)t * 32;
        async16(agp + kof,                   &As[bf * ASZ + sLds]);
        async16(agp + (size_t)64 * K + kof,  &As[bf * ASZ + 2048 + sLds]);
        async16(bgp + kof,                   &Bs[bf * ASZ + sLds]);
        async16(bgp + (size_t)64 * K + kof,  &Bs[bf * ASZ + 2048 + sLds]);
    };

    stage(0, 0);
    stage(1, 1);

    int bf = 0;
    for (int t = 0; t < NT; ++t) {
        if (t < NT - 1) asm volatile("s_waitcnt vmcnt(4)" ::: "memory");
        else            asm volatile("s_waitcnt vmcnt(0)" ::: "memory");
        barrier_fence();
        const int bf2 = (bf + 2 >= 3) ? bf - 1 : bf + 2;
        if (t + 2 < NT) stage(t + 2, bf2);

        const int ab = bf * ASZ + (wm * 64 + fl) * 32 + cSlot;
        // B rows for frag j: wn*32 + (j&1)*16 + (j>>1)*64 + fl
        const int bb = bf * ASZ + (wn * 32 + fl) * 32 + cSlot;
        bf16x8 a[4], b[4];
        #pragma unroll
        for (int mt = 0; mt < 4; ++mt)
            a[mt] = *(const bf16x8*)&As[ab + mt * 512];
        b[0] = *(const bf16x8*)&Bs[bb];
        b[1] = *(const bf16x8*)&Bs[bb + 512];
        b[2] = *(const bf16x8*)&Bs[bb + 2048];
        b[3] = *(const bf16x8*)&Bs[bb + 2560];

        #pragma unroll
        for (int mt = 0; mt < 4; ++mt)
            #pragma unroll
            for (int nt = 0; nt < 4; ++nt)
                acc[mt][nt] = __builtin_amdgcn_mfma_f32_16x16x32_bf16(
                    a[mt], b[nt], acc[mt][nt], 0, 0, 0);

        bf = (bf + 1 >= 3) ? 0 : bf + 1;
    }

    // ---- epilogue: fused RoPE for q/k blocks; vbuf scatter for v ----
    if (n0 < 2560) {
        // rope pair (i, i+64), i = wn*32 + j*16 + fl, j in {0,1}
        const float sc = (n0 < 2048) ? 0.08838834764831845f : 1.0f;
        float inv[2];
        #pragma unroll
        for (int j = 0; j < 2; ++j)
            inv[j] = exp2f(-(float)(wn * 32 + j * 16 + fl) * 0.2076205f); // log2(1e4)/64
        #pragma unroll
        for (int mt = 0; mt < 4; ++mt) {
            #pragma unroll
            for (int r = 0; r < 4; ++r) {
                const int row = m0 + wm * 64 + mt * 16 + q4 * 4 + r;
                const float pos = (float)(row & 2047);
                #pragma unroll
                for (int j = 0; j < 2; ++j) {
                    float s, c;
                    __sincosf(pos * inv[j], &s, &c);
                    const float x1 = acc[mt][j][r];
                    const float x2 = acc[mt][j + 2][r];
                    const int i0 = wn * 32 + j * 16 + fl;
                    C[(size_t)row * 3072 + n0 + i0]      = f2bf((x1 * c - x2 * s) * sc);
                    C[(size_t)row * 3072 + n0 + 64 + i0] = f2bf((x2 * c + x1 * s) * sc);
                }
            }
        }
    } else {
        #pragma unroll
        for (int mt = 0; mt < 4; ++mt)
            #pragma unroll
            for (int j = 0; j < 4; ++j) {
                const int colb = n0 + wn * 32 + (j & 1) * 16 + (j >> 1) * 64 + fl;
                const int f = colb - 2560;
                #pragma unroll
                for (int r = 0; r < 4; ++r) {
                    const int row = m0 + wm * 64 + mt * 16 + q4 * 4 + r;
                    const int tt = row & 2047;
                    const int bb2 = row >> 11;
                    vbuf[((size_t)((bb2 << 2) + (f >> 7)) * 128 + (f & 127)) * 2048 + tt] =
                        f2bf(acc[mt][j][r]);
                }
            }
    }
}

// ---------- GEMM2: Cf = A[M,K] * B[N,K]^T, 128x128 (round-4, frozen) -------
__global__ __launch_bounds__(256, 3)
void gemm128r(const u16* __restrict__ A,
              const u16* __restrict__ B0,
              float* __restrict__ Cf,
              int M, int N, int K)
{
    constexpr int ASZ = 128 * 32;
    __shared__ __align__(16) u16 As[3 * ASZ];
    __shared__ __align__(16) u16 Bs[3 * ASZ];

    const int tid  = threadIdx.x;
    const int w    = tid >> 6;
    const int lane = tid & 63;
    const int fl   = lane & 15;
    const int q4   = lane >> 4;
    const int wm   = w >> 1;
    const int wn   = w & 1;

    const int gx  = gridDim.x;
    const int nwg = gx * gridDim.y;
    int id = blockIdx.y * gx + blockIdx.x;
    id = (id & 7) * (nwg >> 3) + (id >> 3);
    const int m0 = (id / gx) * 128;
    const int n0 = (id % gx) * 128;

    const int srow = w * 16 + (lane >> 2);
    const int sg   = (lane & 3) ^ ((lane >> 3) & 3);
    const u16* agp = A  + (size_t)(m0 + srow) * K + sg * 8;
    const u16* bgp = B0 + (size_t)(n0 + srow) * K + sg * 8;
    const int sLds = w * 512;

    const int cSlot = (q4 ^ ((fl >> 1) & 3)) * 8;

    f32x4 acc[4][4];
    #pragma unroll
    for (int i = 0; i < 4; ++i)
        #pragma unroll
        for (int j = 0; j < 4; ++j)
            acc[i][j] = f32x4{0.f, 0.f, 0.f, 0.f};

    const int NT = K >> 5;

    auto stage = [&](int t, int bf) {
        const size_t kof = (size_t)t * 32;
        async16(agp + kof,                   &As[bf * ASZ + sLds]);
        async16(agp + (size_t)64 * K + kof,  &As[bf * ASZ + 2048 + sLds]);
        async16(bgp + kof,                   &Bs[bf * ASZ + sLds]);
        async16(bgp + (size_t)64 * K + kof,  &Bs[bf * ASZ + 2048 + sLds]);
    };

    stage(0, 0);
    stage(1, 1);

    int bf = 0;
    for (int t = 0; t < NT; ++t) {
        if (t < NT - 1) asm volatile("s_waitcnt vmcnt(4)" ::: "memory");
        else            asm volatile("s_waitcnt vmcnt(0)" ::: "memory");
        barrier_fence();
        const int bf2 = (bf + 2 >= 3) ? bf - 1 : bf + 2;
        if (t + 2 < NT) stage(t + 2, bf2);

        const int ab = bf * ASZ + (wm * 64 + fl) * 32 + cSlot;
        const int bb = bf * ASZ + (wn * 64 + fl) * 32 + cSlot;
        bf16x8 a[4], b[4];
        #pragma unroll
        for (int mt = 0; mt < 4; ++mt)
            a[mt] = *(const bf16x8*)&As[ab + mt * 512];
        #pragma unroll
        for (int nt = 0; nt < 4; ++nt)
            b[nt] = *(const bf16x8*)&Bs[bb + nt * 512];

        #pragma unroll
        for (int mt = 0; mt < 4; ++mt)
            #pragma unroll
            for (int nt = 0; nt < 4; ++nt)
                acc[mt][nt] = __builtin_amdgcn_mfma_f32_16x16x32_bf16(
                    a[mt], b[nt], acc[mt][nt], 0, 0, 0);

        bf = (bf + 1 >= 3) ? 0 : bf + 1;
    }

    #pragma unroll
    for (int mt = 0; mt < 4; ++mt)
        #pragma unroll
        for (int nt = 0; nt < 4; ++nt) {
            const int colb = n0 + wn * 64 + nt * 16 + fl;
            #pragma unroll
            for (int r = 0; r < 4; ++r) {
                const int row = m0 + wm * 64 + mt * 16 + q4 * 4 + r;
                Cf[(size_t)row * N + colb] = acc[mt][nt][r];
            }
        }
}

// ---------- causal flash attention (round-4 LDS-staged version, restored) ---
// Work-paired causal scheme: block handles q-tiles lo=bx and hi=31-bx
// (exactly 33 tile-works per block -> perfect balance, 512 blocks = 2/CU).
// Dual iterations (j<=lo) share every K/V LDS read across 2x MFMA work.
// transposed-S, no-max softmax, deferred l; async dbuf K/V staging w/ XOR swizzle.
__global__ __launch_bounds__(256, 2)
void attn_kernel(const u16* __restrict__ qkv,
                 const u16* __restrict__ vsrc,
                 u16* __restrict__ y)
{
    constexpr int T = 2048;
    const int lo  = blockIdx.x;          // 0..15
    const int hi  = 31 - lo;             // 16..31
    const int bh  = blockIdx.y;
    const int b   = bh >> 4;
    const int h   = bh & 15;
    const int kvh = h >> 2;

    const int tid  = threadIdx.x;
    const int w    = tid >> 6;
    const int lane = tid & 63;
    const int fl   = lane & 15;
    const int q4   = lane >> 4;

    __shared__ __align__(16) u16 Ks[2][64 * 128];   // [kv][d], chunk-swizzled
    __shared__ __align__(16) u16 Vt[2][128 * 64];   // [d][kv], chunk-swizzled
    __shared__ __align__(16) u16 Ps[64 * 72];       // [q][kv], per-wave rows

    const u16* Qg = qkv  + (size_t)(b * T) * 3072 + (h << 7);
    const u16* Kg = qkv  + (size_t)(b * T) * 3072 + 2048 + (kvh << 7);
    const u16* Vg = vsrc + (size_t)((b * 4 + kvh) * 128) * T;

    // Q fragments for both tiles (pre-scaled by 1/sqrt(D) in gemm_qkv)
    bf16x8 qf0[4], qf1[4];
    #pragma unroll
    for (int kc = 0; kc < 4; ++kc) {
        qf0[kc] = *(const bf16x8*)&Qg[(size_t)(lo * 64 + w * 16 + fl) * 3072 + kc * 32 + q4 * 8];
        qf1[kc] = *(const bf16x8*)&Qg[(size_t)(hi * 64 + w * 16 + fl) * 3072 + kc * 32 + q4 * 8];
    }

    // staging: per-lane swizzled global offsets, wave-uniform LDS chunk bases
    int goffK[4], goffV[4], ldsC[4];
    #pragma unroll
    for (int i = 0; i < 4; ++i) {
        const int c  = w + 4 * i;                 // 1KB chunk 0..15
        const int rk = 4 * c + (lane >> 4);       // K row in tile
        const int lk = (lane & 15) ^ (rk & 15);
        goffK[i] = rk * 3072 + lk * 8;
        const int rv = 8 * c + (lane >> 3);       // V row (d index)
        const int lv = (lane & 7) ^ ((lane >> 3) & 7);
        goffV[i] = rv * T + lv * 8;
        ldsC[i]  = c * 512;
    }

    #pragma unroll
    for (int i = 0; i < 4; ++i) {                 // prefetch tile 0 -> buf 0
        async16(Kg + goffK[i], &Ks[0][ldsC[i]]);
        async16(Vg + goffV[i], &Vt[0][ldsC[i]]);
    }

    float l0 = 0.f, l1 = 0.f;                     // per-lane partial sums
    f32x4 o0[8], o1[8];
    #pragma unroll
    for (int dt = 0; dt < 8; ++dt) {
        o0[dt] = f32x4{0.f, 0.f, 0.f, 0.f};
        o1[dt] = f32x4{0.f, 0.f, 0.f, 0.f};
    }

    const int psrow = (w * 16 + fl) * 72;

    for (int j = 0; j <= hi; ++j) {
        __syncthreads();   // drains vmcnt: buf[j&1] ready; buf[j^1] released

        if (j < hi) {      // prefetch j+1, in flight during compute
            const u16* kb = Kg + (size_t)(j + 1) * 64 * 3072;
            const u16* vb = Vg + (j + 1) * 64;
            const int nb = (j + 1) & 1;
            #pragma unroll
            for (int i = 0; i < 4; ++i) {
                async16(kb + goffK[i], &Ks[nb][ldsC[i]]);
                async16(vb + goffV[i], &Vt[nb][ldsC[i]]);
            }
        }
        const int cb = j & 1;
        const bool dual = (j <= lo);

        // S^T = K * Q^T for ctx1 (always) and ctx0 (dual), sharing aK reads
        f32x4 s0[4], s1[4];
        #pragma unroll
        for (int nt = 0; nt < 4; ++nt) {
            s0[nt] = f32x4{0.f, 0.f, 0.f, 0.f};
            s1[nt] = f32x4{0.f, 0.f, 0.f, 0.f};
        }
        if (dual) {
            #pragma unroll
            for (int kc = 0; kc < 4; ++kc)
                #pragma unroll
                for (int nt = 0; nt < 4; ++nt) {
                    bf16x8 aK = *(const bf16x8*)
                        &Ks[cb][(nt * 16 + fl) * 128 + (((kc << 2) + q4) ^ fl) * 8];
                    s1[nt] = __builtin_amdgcn_mfma_f32_16x16x32_bf16(aK, qf1[kc], s1[nt], 0, 0, 0);
                    s0[nt] = __builtin_amdgcn_mfma_f32_16x16x32_bf16(aK, qf0[kc], s0[nt], 0, 0, 0);
                }
        } else {
            #pragma unroll
            for (int kc = 0; kc < 4; ++kc)
                #pragma unroll
                for (int nt = 0; nt < 4; ++nt) {
                    bf16x8 aK = *(const bf16x8*)
                        &Ks[cb][(nt * 16 + fl) * 128 + (((kc << 2) + q4) ^ fl) * 8];
                    s1[nt] = __builtin_amdgcn_mfma_f32_16x16x32_bf16(aK, qf1[kc], s1[nt], 0, 0, 0);
                }
        }

        // causal masks (diagonal tiles only; j==lo is always dual, j==hi never)
        if (j == lo || j == hi) {
            const int qloc = w * 16 + fl;
            #pragma unroll
            for (int nt = 0; nt < 4; ++nt)
                #pragma unroll
                for (int r = 0; r < 4; ++r)
                    if (nt * 16 + q4 * 4 + r > qloc) {
                        if (j == lo) s0[nt][r] = -3e38f;
                        else         s1[nt][r] = -3e38f;
                    }
        }

        // ctx0 (dual only): exp + P write + PV
        if (dual) {
            #pragma unroll
            for (int nt = 0; nt < 4; ++nt) {
                ushort4 pw;
                float p0 = __expf(s0[nt][0]);
                float p1 = __expf(s0[nt][1]);
                float p2 = __expf(s0[nt][2]);
                float p3 = __expf(s0[nt][3]);
                l0 += (p0 + p1) + (p2 + p3);
                pw.x = f2bf(p0); pw.y = f2bf(p1); pw.z = f2bf(p2); pw.w = f2bf(p3);
                *(ushort4*)&Ps[psrow + nt * 16 + q4 * 4] = pw;
            }
            asm volatile("s_waitcnt lgkmcnt(0)" ::: "memory");
            #pragma unroll
            for (int kc = 0; kc < 2; ++kc) {
                bf16x8 ap = *(const bf16x8*)&Ps[psrow + kc * 32 + q4 * 8];
                #pragma unroll
                for (int dt = 0; dt < 8; ++dt) {
                    bf16x8 bv = *(const bf16x8*)
                        &Vt[cb][(dt * 16 + fl) * 64 + (((kc << 2) + q4) ^ (fl & 7)) * 8];
                    o0[dt] = __builtin_amdgcn_mfma_f32_16x16x32_bf16(ap, bv, o0[dt], 0, 0, 0);
                }
            }
        }

        // ctx1: exp + P write (same per-wave Ps rows; DS pipe is in-order
        // per wave, so prior ap reads complete before these writes land) + PV
        #pragma unroll
        for (int nt = 0; nt < 4; ++nt) {
            ushort4 pw;
            float p0 = __expf(s1[nt][0]);
            float p1 = __expf(s1[nt][1]);
            float p2 = __expf(s1[nt][2]);
            float p3 = __expf(s1[nt][3]);
            l1 += (p0 + p1) + (p2 + p3);
            pw.x = f2bf(p0); pw.y = f2bf(p1); pw.z = f2bf(p2); pw.w = f2bf(p3);
            *(ushort4*)&Ps[psrow + nt * 16 + q4 * 4] = pw;
        }
        asm volatile("s_waitcnt lgkmcnt(0)" ::: "memory");
        #pragma unroll
        for (int kc = 0; kc < 2; ++kc) {
            bf16x8 ap = *(const bf16x8*)&Ps[psrow + kc * 32 + q4 * 8];
            #pragma unroll
            for (int dt = 0; dt < 8; ++dt) {
                bf16x8 bv = *(const bf16x8*)
                    &Vt[cb][(dt * 16 + fl) * 64 + (((kc << 2) + q4) ^ (fl & 7)) * 8];
                o1[dt] = __builtin_amdgcn_mfma_f32_16x16x32_bf16(ap, bv, o1[dt], 0, 0, 0);
            }
        }
    }

    // deferred l reductions + epilogue for both contexts
    l0 += __shfl_xor(l0, 16, 64);
    l0 += __shfl_xor(l0, 32, 64);
    l1 += __shfl_xor(l1, 16, 64);
    l1 += __shfl_xor(l1, 32, 64);
    const float li0 = 1.0f / l0;
    const float li1 = 1.0f / l1;

    float lr0[4], lr1[4];
    #pragma unroll
    for (int r = 0; r < 4; ++r) {
        lr0[r] = __shfl(li0, q4 * 4 + r, 16);
        lr1[r] = __shfl(li1, q4 * 4 + r, 16);
    }
    #pragma unroll
    for (int dt = 0; dt < 8; ++dt)
        #pragma unroll
        for (int r = 0; r < 4; ++r) {
            const int row0 = lo * 64 + w * 16 + q4 * 4 + r;
            const int row1 = hi * 64 + w * 16 + q4 * 4 + r;
            y[(size_t)(b * T + row0) * 2048 + (h << 7) + dt * 16 + fl] =
                f2bf(o0[dt][r] * lr0[r]);
            y[(size_t)(b * T + row1) * 2048 + (h << 7) + dt * 16 + fl] =
                f2bf(o1[dt][r] * lr1[r]);
        }
}

// ---------- launch ----------------------------------------------------------
extern "C" void kernel_launch(void* const* d_in, const int* in_sizes, int n_in,
                              void* d_out, int out_size, void* d_ws, size_t ws_size,
                              hipStream_t stream)
{
    const float* x   = (const float*)d_in[0];
    const float* Wq  = (const float*)d_in[1];
    const float* Wkv = (const float*)d_in[2];
    const float* Wo  = (const float*)d_in[3];
    float* out = (float*)d_out;

    const int nx = 4096 * 2048, nq = 2048 * 2048, nkv = 1024 * 2048, no = 2048 * 2048;

    u16* xb   = (u16*)d_ws;
    u16* wqb  = xb  + nx;
    u16* wkvb = wqb + nq;
    u16* wob  = wkvb + nkv;
    u16* qkv  = wob + no;                            // [4096, 3072]
    u16* vbuf = qkv + (size_t)4096 * 3072;           // V^T [B*KV*128, 2048]
    u16* y    = vbuf + (size_t)2 * 4 * 128 * 2048;   // [4096, 2048]

    const int ntot = nx + nq + nkv + no;
    cvt_all<<<ntot / 1024, 256, 0, stream>>>(x, Wq, Wkv, Wo, xb, wqb, wkvb, wob);

    dim3 g1(3072 / 128, 4096 / 128);                 // 24 x 32 = 768 wgs (%8==0)
    gemm_qkv<<<g1, 256, 0, stream>>>(xb, wqb, wkvb, qkv, vbuf, 4096, 2048);

    attn_kernel<<<dim3(16, 32), 256, 0, stream>>>(qkv, vbuf, y);

    dim3 g2(2048 / 128, 4096 / 128);                 // 16 x 32 = 512 wgs (%8==0)
    gemm128r<<<g2, 256, 0, stream>>>(y, wob, out, 4096, 2048, 2048);
}